// Round 5
// baseline (41279.617 us; speedup 1.0000x reference)
//
#include <hip/hip_runtime.h>

// LSTM(H=1024) over SEQ=8192, input_size=1, persistent kernel, round 4 resubmit
// (round 4 never ran: GPU acquisition timeout).
// 64 wgs x 512 threads (1 wg/CU). Global wave Wv = 8g+w owns h-pair
// (2Wv, 2Wv+1) = 8 gate rows of W_hh, held in 128 AGPRs/thread via VOLATILE
// v_accvgpr_write/read (volatile reads can't be hoisted -> no VGPR blowup,
// no scratch spill — round 3's non-volatile reads were hoisted and spilled).
// Sync redesign: publishers store untagged (h0,h1) 8B slots (sc1) ->
// __syncthreads (vmcnt drain => slots at MALL) -> tid0 stores flags[g]=t+1.
// Readers poll ONLY the 64-flag array (256 B/wave/iter, s_sleep paced)
// instead of the 8 KB tagged-slot array: ~16x less poll traffic on the MALL,
// which round 3's counters showed was the bottleneck (~25 poll iters/step).

#define SEQ 8192
#define HID 1024
#define NWG 64
#define TPB 512
#define NWAVE 8   // waves per workgroup

typedef unsigned long long ull;

__device__ __forceinline__ float fast_sigmoid(float z) {
    float e = __builtin_amdgcn_exp2f(-1.4426950408889634f * z);
    return 1.0f / (1.0f + e);
}
__device__ __forceinline__ float fast_tanh(float x) {
    float e = __builtin_amdgcn_exp2f(2.8853900817779268f * x);
    return 1.0f - 2.0f / (e + 1.0f);
}

// ws/out re-poisoned 0xAA before every launch: zero flags, prefill out=b_lin.
// Slots need no init (reads are flag-gated; step 0 reads nothing).
__global__ void init_kernel(unsigned* flags, float* out, const float* __restrict__ b_lin) {
    int i = blockIdx.x * blockDim.x + threadIdx.x;
    if (i < NWG) flags[i] = 0u;
    if (i < SEQ) out[i] = b_lin[0];
}

__global__ void finish_kernel(const float* __restrict__ partials,
                              float* __restrict__ out) {
    int t = blockIdx.x * blockDim.x + threadIdx.x;
    if (t >= SEQ) return;
    float s = out[t];  // b_lin from init
    #pragma unroll 4
    for (int g2 = 0; g2 < NWG; ++g2) s += partials[(size_t)g2 * SEQ + t];
    out[t] = s;
}

__global__ __launch_bounds__(TPB, 2)
void lstm_kernel(const float* __restrict__ sentence,
                 const float* __restrict__ W_ih,
                 const float* __restrict__ W_hh,
                 const float* __restrict__ b_ih,
                 const float* __restrict__ b_hh,
                 const float* __restrict__ W_lin,
                 unsigned* flags, ull* slots,
                 float* partials, float* out, int use_partials)
{
    __shared__ float s_sent[SEQ];       // 32 KiB
    __shared__ float s_h[HID];          // 4 KiB staged h_{t-1}
    __shared__ float s_part[2][NWAVE];
    const int tid = threadIdx.x;
    const int g = blockIdx.x;
    const int w = tid >> 6;
    const int l = tid & 63;
    const int Wv = g * NWAVE + w;       // global wave 0..511
    const int j0 = 2 * Wv, j1 = 2 * Wv + 1;

    for (int i = tid; i < SEQ; i += TPB) s_sent[i] = sentence[i];

    // 8 gate rows (4 for j0, 4 for j1) into 128 AGPRs/thread.
    // Lane l holds columns {k*64+l : k=0..15} of each row.
    float Wa[8][16];
    #pragma unroll
    for (int r = 0; r < 8; ++r) {
        const int row = ((r < 4) ? j0 : j1) + (r & 3) * HID;
        const float* rowp = W_hh + (size_t)row * HID;
        #pragma unroll
        for (int k = 0; k < 16; ++k) {
            float tmp = rowp[k * 64 + l];
            asm volatile("v_accvgpr_write_b32 %0, %1" : "=a"(Wa[r][k]) : "v"(tmp));
        }
    }
    float wih[8], bb[8];
    #pragma unroll
    for (int r = 0; r < 8; ++r) {
        const int row = ((r < 4) ? j0 : j1) + (r & 3) * HID;
        wih[r] = W_ih[row];
        bb[r]  = b_ih[row] + b_hh[row];
    }
    const float wlin0 = W_lin[j0], wlin1 = W_lin[j1];
    float c0 = 0.0f, c1 = 0.0f;

    ull* const buf0 = slots;            // 512 x 8B per buffer
    ull* const buf1 = slots + (HID / 2);

    __syncthreads();  // sentence staged

    for (int t = 0; t < SEQ; ++t) {
        if (t == 0) {
            s_h[2 * tid] = 0.0f;
            s_h[2 * tid + 1] = 0.0f;
        } else {
            // Drain previous step's output partial on wave 1 (overlaps polls).
            if (w == 1 && l == 0) {
                const float* sp = s_part[(t - 1) & 1];
                float p = sp[0] + sp[1] + sp[2] + sp[3] + sp[4] + sp[5] + sp[6] + sp[7];
                if (use_partials) partials[(size_t)g * SEQ + (t - 1)] = p;
                else atomicAdd(&out[t - 1], p);
            }
            // Poll the 64-flag summary (1 dword/lane/iter), s_sleep paced.
            const unsigned tt = (unsigned)t;
            int guard = 0;
            for (;;) {
                unsigned f = __hip_atomic_load(&flags[l], __ATOMIC_RELAXED, __HIP_MEMORY_SCOPE_AGENT);
                if (__all((int)(f >= tt))) break;
                if (++guard > (1 << 22)) break;  // fail loud, don't hang
                __builtin_amdgcn_s_sleep(1);
            }
            // Flags at MALL imply slots at MALL (store order: slots -> barrier
            // vmcnt-drain -> flag). One 8B bypass load per thread gets h-pair.
            ull v = __hip_atomic_load(&((t & 1) ? buf1 : buf0)[tid],
                                      __ATOMIC_RELAXED, __HIP_MEMORY_SCOPE_AGENT);
            s_h[2 * tid]     = __uint_as_float((unsigned)v);
            s_h[2 * tid + 1] = __uint_as_float((unsigned)(v >> 32));
        }
        __syncthreads();

        // ---- z[r] = W_row[r] . h for this wave's 8 gate rows ----
        float acc[8] = {0.f, 0.f, 0.f, 0.f, 0.f, 0.f, 0.f, 0.f};
        #pragma unroll
        for (int k = 0; k < 16; ++k) {
            const float hk = s_h[k * 64 + l];
            #pragma unroll
            for (int r = 0; r < 8; ++r) {
                float wr;
                asm volatile("v_accvgpr_read_b32 %0, %1" : "=v"(wr) : "a"(Wa[r][k]));
                acc[r] = fmaf(wr, hk, acc[r]);
            }
        }
        #pragma unroll
        for (int m = 1; m < 64; m <<= 1) {
            #pragma unroll
            for (int r = 0; r < 8; ++r) acc[r] += __shfl_xor(acc[r], m, 64);
        }

        const float x = s_sent[t];
        // j0: gates i,f,g,o = acc[0..3]; j1: acc[4..7]
        float zi0 = fmaf(wih[0], x, acc[0] + bb[0]);
        float zf0 = fmaf(wih[1], x, acc[1] + bb[1]);
        float zg0 = fmaf(wih[2], x, acc[2] + bb[2]);
        float zo0 = fmaf(wih[3], x, acc[3] + bb[3]);
        float zi1 = fmaf(wih[4], x, acc[4] + bb[4]);
        float zf1 = fmaf(wih[5], x, acc[5] + bb[5]);
        float zg1 = fmaf(wih[6], x, acc[6] + bb[6]);
        float zo1 = fmaf(wih[7], x, acc[7] + bb[7]);
        c0 = fmaf(fast_sigmoid(zf0), c0, fast_sigmoid(zi0) * fast_tanh(zg0));
        c1 = fmaf(fast_sigmoid(zf1), c1, fast_sigmoid(zi1) * fast_tanh(zg1));
        const float hn0 = fast_sigmoid(zo0) * fast_tanh(c0);
        const float hn1 = fast_sigmoid(zo1) * fast_tanh(c1);

        // ---- publish h-pair (one 8B sc1 store per wave) ----
        if (l == 0) {
            ull pk = ((ull)__float_as_uint(hn1) << 32) | (ull)__float_as_uint(hn0);
            __hip_atomic_store(&(((t + 1) & 1) ? buf1 : buf0)[Wv], pk,
                               __ATOMIC_RELAXED, __HIP_MEMORY_SCOPE_AGENT);
            s_part[t & 1][w] = fmaf(wlin0, hn0, wlin1 * hn1);
        }
        __syncthreads();  // per-wave vmcnt(0) drain: all 8 slot stores at MALL
        if (tid == 0)
            __hip_atomic_store(&flags[g], (unsigned)(t + 1),
                               __ATOMIC_RELAXED, __HIP_MEMORY_SCOPE_AGENT);
    }

    if (tid == 0) {  // final step's output partial
        const float* sp = s_part[(SEQ - 1) & 1];
        float p = sp[0] + sp[1] + sp[2] + sp[3] + sp[4] + sp[5] + sp[6] + sp[7];
        if (use_partials) partials[(size_t)g * SEQ + (SEQ - 1)] = p;
        else atomicAdd(&out[SEQ - 1], p);
    }
}

extern "C" void kernel_launch(void* const* d_in, const int* in_sizes, int n_in,
                              void* d_out, int out_size, void* d_ws, size_t ws_size,
                              hipStream_t stream) {
    const float* sentence = (const float*)d_in[0];
    const float* W_ih     = (const float*)d_in[1];
    const float* W_hh     = (const float*)d_in[2];
    const float* b_ih     = (const float*)d_in[3];
    const float* b_hh     = (const float*)d_in[4];
    const float* W_lin    = (const float*)d_in[5];
    const float* b_lin    = (const float*)d_in[6];
    float* out = (float*)d_out;

    char* ws = (char*)d_ws;
    unsigned* flags = (unsigned*)ws;                       // 256 B (64 flags)
    ull* slots      = (ull*)(ws + 512);                    // 8 KiB (2 x 512 x 8B)
    float* partials = (float*)(ws + 512 + 2 * (HID / 2) * sizeof(ull));
    const size_t need = 512 + 2 * (HID / 2) * sizeof(ull) + (size_t)NWG * SEQ * sizeof(float);
    int use_partials = (ws_size >= need) ? 1 : 0;          // fallback: atomicAdd

    hipLaunchKernelGGL(init_kernel, dim3(SEQ / 256), dim3(256), 0, stream,
                       flags, out, b_lin);
    hipLaunchKernelGGL(lstm_kernel, dim3(NWG), dim3(TPB), 0, stream,
                       sentence, W_ih, W_hh, b_ih, b_hh, W_lin,
                       flags, slots, partials, out, use_partials);
    if (use_partials) {
        hipLaunchKernelGGL(finish_kernel, dim3(SEQ / 256), dim3(256), 0, stream,
                           partials, out);
    }
}

// Round 7
// 31076.688 us; speedup vs baseline: 1.3283x; 1.3283x over previous
//
#include <hip/hip_runtime.h>

// LSTM(H=1024) over SEQ=8192, input_size=1, persistent kernel, round 6
// resubmit (round 6 never ran: GPU acquisition timeout).
// Composition of the two proven-good pieces:
//  - round-2 sync protocol: (tag,h) packed in ONE 8B slot, double-buffered,
//    relaxed agent-scope atomics -> ONE MALL round trip per step after
//    publish visibility (round 5's flag protocol added a second RT: regressed).
//  - round-5 W residency: 64 W floats/thread pinned in AGPRs via VOLATILE
//    v_accvgpr_write/read (VGPR_Count=88, FETCH collapsed => register-resident).
// Machine: 128 wgs x 512 threads (1 wg/CU), wave Wv=8g+w owns h-index j=Wv
// (4 gate rows, 64 AGPRs). Per-lane early poll exit: lanes whose slots are
// tagged stop issuing poll loads.

#define SEQ 8192
#define HID 1024
#define NWG 128
#define TPB 512
#define NWAVE 8

typedef unsigned long long ull;

__device__ __forceinline__ float fast_sigmoid(float z) {
    float e = __builtin_amdgcn_exp2f(-1.4426950408889634f * z);
    return 1.0f / (1.0f + e);
}
__device__ __forceinline__ float fast_tanh(float x) {
    float e = __builtin_amdgcn_exp2f(2.8853900817779268f * x);
    return 1.0f - 2.0f / (e + 1.0f);
}

// ws/out re-poisoned 0xAA each launch. Slots need no init: poisoned tag
// 0xAAAAAAAA never equals a live tag (1..SEQ), and tags strictly increase
// within a launch. Only out[] needs the b_lin prefill.
__global__ void init_kernel(float* out, const float* __restrict__ b_lin) {
    int i = blockIdx.x * blockDim.x + threadIdx.x;
    if (i < SEQ) out[i] = b_lin[0];
}

__global__ void finish_kernel(const float* __restrict__ partials,
                              float* __restrict__ out) {
    int t = blockIdx.x * blockDim.x + threadIdx.x;
    if (t >= SEQ) return;
    float s = out[t];  // b_lin from init
    #pragma unroll 4
    for (int g2 = 0; g2 < NWG; ++g2) s += partials[(size_t)g2 * SEQ + t];
    out[t] = s;
}

__global__ __launch_bounds__(TPB, 2)
void lstm_kernel(const float* __restrict__ sentence,
                 const float* __restrict__ W_ih,
                 const float* __restrict__ W_hh,
                 const float* __restrict__ b_ih,
                 const float* __restrict__ b_hh,
                 const float* __restrict__ W_lin,
                 ull* slots, float* partials, float* out, int use_partials)
{
    __shared__ float s_sent[SEQ];      // 32 KiB: whole input, read once
    __shared__ float s_h[HID];         // staged h_{t-1}
    __shared__ float s_part[2][NWAVE]; // per-wave W_lin partials, dbuf'd
    const int tid = threadIdx.x;
    const int g = blockIdx.x;
    const int w = tid >> 6;
    const int l = tid & 63;
    const int j = g * NWAVE + w;       // this wave's h-index (0..1023)

    for (int i = tid; i < SEQ; i += TPB) s_sent[i] = sentence[i];

    // 4 gate rows of W_hh into 64 AGPRs/thread. Lane l holds columns
    // {k*64+l : k=0..15} of each row. Volatile write AND read: regalloc can
    // neither spill nor hoist (round 3's non-volatile reads were hoisted
    // -> VGPR blowup -> scratch; round 5 proved this form stays resident).
    float Wa[4][16];
    #pragma unroll
    for (int gate = 0; gate < 4; ++gate) {
        const float* rowp = W_hh + (size_t)(j + gate * HID) * HID;
        #pragma unroll
        for (int k = 0; k < 16; ++k) {
            float tmp = rowp[k * 64 + l];
            asm volatile("v_accvgpr_write_b32 %0, %1" : "=a"(Wa[gate][k]) : "v"(tmp));
        }
    }
    float wih[4], bb[4];
    #pragma unroll
    for (int gate = 0; gate < 4; ++gate) {
        int row = j + gate * HID;
        wih[gate] = W_ih[row];
        bb[gate]  = b_ih[row] + b_hh[row];
    }
    const float wlin = W_lin[j];
    float c = 0.0f;

    ull* const buf0 = slots;           // 1024 slots x 8B per buffer
    ull* const buf1 = slots + HID;

    __syncthreads();  // sentence staged

    for (int t = 0; t < SEQ; ++t) {
        // ---- acquire h_{t-1} into LDS (single-RT tagged-slot protocol) ----
        if (t == 0) {
            s_h[tid] = 0.0f;
            s_h[tid + TPB] = 0.0f;
        } else {
            ull* b = (t & 1) ? buf1 : buf0;
            const unsigned tt = (unsigned)t;
            float h0 = 0.0f, h1 = 0.0f;
            bool d0 = false, d1 = false;
            int guard = 0;
            for (;;) {
                if (!d0) {
                    ull v = __hip_atomic_load(&b[tid], __ATOMIC_RELAXED, __HIP_MEMORY_SCOPE_AGENT);
                    if ((unsigned)(v >> 32) == tt) { h0 = __uint_as_float((unsigned)v); d0 = true; }
                }
                if (!d1) {
                    ull v = __hip_atomic_load(&b[tid + TPB], __ATOMIC_RELAXED, __HIP_MEMORY_SCOPE_AGENT);
                    if ((unsigned)(v >> 32) == tt) { h1 = __uint_as_float((unsigned)v); d1 = true; }
                }
                if (d0 && d1) break;
                if (++guard > (1 << 24)) break;  // fail loud, don't hang
            }
            s_h[tid]       = h0;
            s_h[tid + TPB] = h1;
        }
        __syncthreads();

        // Drain previous step's output partial (post-barrier: s_part[t-1] is
        // complete; one thread, 8 LDS reads + one 4B store — off critical path).
        if (t > 0 && tid == 0) {
            const float* sp = s_part[(t - 1) & 1];
            float p = sp[0] + sp[1] + sp[2] + sp[3] + sp[4] + sp[5] + sp[6] + sp[7];
            if (use_partials) partials[(size_t)g * SEQ + (t - 1)] = p;
            else atomicAdd(&out[t - 1], p);
        }

        // ---- z = W_hh[rows of j] . h (wave-wide, W from AGPRs) ----
        float acc0 = 0.f, acc1 = 0.f, acc2 = 0.f, acc3 = 0.f;
        #pragma unroll
        for (int k = 0; k < 16; ++k) {
            const float hk = s_h[k * 64 + l];
            float w0, w1, w2, w3;
            asm volatile("v_accvgpr_read_b32 %0, %1" : "=v"(w0) : "a"(Wa[0][k]));
            asm volatile("v_accvgpr_read_b32 %0, %1" : "=v"(w1) : "a"(Wa[1][k]));
            asm volatile("v_accvgpr_read_b32 %0, %1" : "=v"(w2) : "a"(Wa[2][k]));
            asm volatile("v_accvgpr_read_b32 %0, %1" : "=v"(w3) : "a"(Wa[3][k]));
            acc0 = fmaf(w0, hk, acc0);
            acc1 = fmaf(w1, hk, acc1);
            acc2 = fmaf(w2, hk, acc2);
            acc3 = fmaf(w3, hk, acc3);
        }
        #pragma unroll
        for (int m = 1; m < 64; m <<= 1) {
            acc0 += __shfl_xor(acc0, m, 64);
            acc1 += __shfl_xor(acc1, m, 64);
            acc2 += __shfl_xor(acc2, m, 64);
            acc3 += __shfl_xor(acc3, m, 64);
        }

        const float x = s_sent[t];
        float zi = fmaf(wih[0], x, acc0 + bb[0]);
        float zf = fmaf(wih[1], x, acc1 + bb[1]);
        float zg = fmaf(wih[2], x, acc2 + bb[2]);
        float zo = fmaf(wih[3], x, acc3 + bb[3]);
        c = fmaf(fast_sigmoid(zf), c, fast_sigmoid(zi) * fast_tanh(zg));
        const float hn = fast_sigmoid(zo) * fast_tanh(c);

        // ---- publish (tag=t+1, h_t[j]) — one 8B store, fire-and-forget ----
        if (l == 0) {
            ull pk = ((ull)(unsigned)(t + 1) << 32) | (ull)__float_as_uint(hn);
            __hip_atomic_store(&(((t + 1) & 1) ? buf1 : buf0)[j], pk,
                               __ATOMIC_RELAXED, __HIP_MEMORY_SCOPE_AGENT);
            s_part[t & 1][w] = wlin * hn;
        }
        // No barrier here: distance-2 buffer-reuse safety (a wave reaching
        // step t+1's publish has observed ALL step-t tags, so every wg is
        // past step t-1's reads of the buffer being overwritten).
    }

    __syncthreads();
    if (tid == 0) {  // final step's output partial
        const float* sp = s_part[(SEQ - 1) & 1];
        float p = sp[0] + sp[1] + sp[2] + sp[3] + sp[4] + sp[5] + sp[6] + sp[7];
        if (use_partials) partials[(size_t)g * SEQ + (SEQ - 1)] = p;
        else atomicAdd(&out[SEQ - 1], p);
    }
}

extern "C" void kernel_launch(void* const* d_in, const int* in_sizes, int n_in,
                              void* d_out, int out_size, void* d_ws, size_t ws_size,
                              hipStream_t stream) {
    const float* sentence = (const float*)d_in[0];
    const float* W_ih     = (const float*)d_in[1];
    const float* W_hh     = (const float*)d_in[2];
    const float* b_ih     = (const float*)d_in[3];
    const float* b_hh     = (const float*)d_in[4];
    const float* W_lin    = (const float*)d_in[5];
    const float* b_lin    = (const float*)d_in[6];
    float* out = (float*)d_out;

    char* ws = (char*)d_ws;
    ull* slots      = (ull*)ws;                          // 16 KiB (2 x 1024 x 8B)
    float* partials = (float*)(ws + 2 * HID * sizeof(ull));
    const size_t need = 2 * HID * sizeof(ull) + (size_t)NWG * SEQ * sizeof(float);
    int use_partials = (ws_size >= need) ? 1 : 0;        // fallback: atomicAdd

    hipLaunchKernelGGL(init_kernel, dim3(SEQ / 256), dim3(256), 0, stream,
                       out, b_lin);
    hipLaunchKernelGGL(lstm_kernel, dim3(NWG), dim3(TPB), 0, stream,
                       sentence, W_ih, W_hh, b_ih, b_hh, W_lin,
                       slots, partials, out, use_partials);
    if (use_partials) {
        hipLaunchKernelGGL(finish_kernel, dim3(SEQ / 256), dim3(256), 0, stream,
                           partials, out);
    }
}